// Round 21
// baseline (931.394 us; speedup 1.0000x reference)
//
#include <hip/hip_runtime.h>
#include <hip/hip_bf16.h>

// out[M,N] = X[M,K] @ W[K,N] + (X@A)@B + bias;  M=16384, N=K=4096.
// P1: X -> bf16.  P2: Wt[n][k] = bf16(W[k][n] + lora).  G: 256x256 MFMA GEMM,
// TWO barriers + ONE vmcnt per K-tile: every region = {32-MFMA cluster +
// next-region ds_reads + one 4-load stage slot}.  LDS-coalesced epilogue (R20).

typedef __attribute__((ext_vector_type(8))) __bf16 bf16x8;
typedef __attribute__((ext_vector_type(4))) float f32x4;

#define M_DIM 16384
#define N_DIM 4096
#define K_DIM 4096

__device__ __forceinline__ void async16(const void* g, void* l) {
    __builtin_amdgcn_global_load_lds((const __attribute__((address_space(1))) void*)g,
                                     (__attribute__((address_space(3))) void*)l,
                                     16, 0, 0);
}

// ---------------- P1: cast X to bf16 ----------------
__global__ void cast_x_kernel(const float* __restrict__ x, __bf16* __restrict__ xb, size_t n) {
    size_t i0 = ((size_t)blockIdx.x * blockDim.x + threadIdx.x) * 8;
    size_t stride = (size_t)gridDim.x * blockDim.x * 8;
    for (size_t i = i0; i < n; i += stride) {
        f32x4 v0 = __builtin_nontemporal_load((const f32x4*)(x + i));
        f32x4 v1 = __builtin_nontemporal_load((const f32x4*)(x + i + 4));
        bf16x8 o;
        o[0] = (__bf16)v0[0]; o[1] = (__bf16)v0[1]; o[2] = (__bf16)v0[2]; o[3] = (__bf16)v0[3];
        o[4] = (__bf16)v1[0]; o[5] = (__bf16)v1[1]; o[6] = (__bf16)v1[2]; o[7] = (__bf16)v1[3];
        *(bf16x8*)(xb + i) = o;
    }
}

// ---------------- P2: Wt[n][k] = bf16(W[k][n] + lora) ----------------
__global__ void prep_w_kernel(const float* __restrict__ W, const float* __restrict__ A,
                              const float* __restrict__ Bm, __bf16* __restrict__ Wt) {
    __shared__ float Ws[32][33];
    __shared__ float As[32][16];
    __shared__ float Bs[16][32];
    const int tx = threadIdx.x;
    const int ty = threadIdx.y;
    const int t = ty * 32 + tx;
    const int n0 = blockIdx.x * 32;
    const int k0 = blockIdx.y * 32;

#pragma unroll
    for (int i = 0; i < 4; ++i) {
        int k = ty + i * 8;
        Ws[k][tx] = W[(size_t)(k0 + k) * N_DIM + n0 + tx];
    }
    for (int i = t; i < 512; i += 256)
        As[i >> 4][i & 15] = A[(size_t)(k0 + (i >> 4)) * 16 + (i & 15)];
    for (int i = t; i < 512; i += 256)
        Bs[i >> 5][i & 31] = Bm[(size_t)(i >> 5) * N_DIM + n0 + (i & 31)];
    __syncthreads();

    float a[16];
#pragma unroll
    for (int r = 0; r < 16; ++r) a[r] = As[tx][r];
#pragma unroll
    for (int i = 0; i < 4; ++i) {
        int n = ty + i * 8;
        float acc = Ws[tx][n];
#pragma unroll
        for (int r = 0; r < 16; ++r) acc += a[r] * Bs[r][n];
        Wt[(size_t)(n0 + n) * K_DIM + k0 + tx] = (__bf16)acc;
    }
}

// ---------------- G: 256x256, 2-barrier / 1-vmcnt K-tiles ----------------
// 512 threads = 8 waves (2 wr x 4 wn). Per wave 128x64 out = 8x4 frags of 16x16.
// LDS: 2 bufs x (A[256][64] + B[256][64]) bf16 = 128 KiB, col-swizzle g -> g^(row&7).
// B rows nh-permuted: phys p = nh*128 + wn*32 + s.
// Tile t: AC=A[t%2], BC=B[t%2].  Regions (each = MFMA cluster + next reads + stage):
//  [BAR-A(t)]  MFMA(afr0 x b0f,b1f) [32]; ds{afr1 from AC};
//              ST B(t+2)->BC; VM(4); [BAR-B(t)]
//              MFMA(afr1 x b1f,b0f) [32]; ds{afr0,b0f,b1f from AO/BO};
//              ST A(t+2)->AC;          [BAR-A(t+1)]
// FIFO (4 loads/slot): after BAR-A(t) = [B(t+1) 4, A(t+1) 4]; +B(t+2) -> 12;
//   VM(4) drains B(t+1)+A(t+1) (read next region, barrier-separated); +A(t+2)
//   -> 8 = invariant.  ONE vmcnt per K-tile.
// WAR (>=1 barrier between readers' issue and stage, all waves):
//   B(t+2)->BC: readers b0f/b1f(t) issued before BAR-A(t), stage after it.
//   A(t+2)->AC: readers afr1(t) issued before BAR-B(t), stage after it.
// Tails: t62 VM(0) (drains A(63)+B(63)); t63 barrier-free; epilogue BARRIER.

#define WAIT_VM(N) asm volatile("s_waitcnt vmcnt(" #N ")" ::: "memory")
#define BARRIER() do { asm volatile("" ::: "memory"); __builtin_amdgcn_s_barrier(); asm volatile("" ::: "memory"); } while (0)

#define ST(ptr, koff, ldsbase, row0) \
    async16((ptr) + (koff), (ldsbase) + (row0) * 128 + sldsoff)

#define LOAD_AF(dst, ldsbase, MH)                                                    \
    _Pragma("unroll") for (int m_ = 0; m_ < 4; ++m_)                                 \
    _Pragma("unroll") for (int ks_ = 0; ks_ < 2; ++ks_)                              \
        dst[m_][ks_] = *(const bf16x8*)((ldsbase) + aRowB + (MH) * 8192 + m_ * 2048 + colsw[ks_]);

#define LOAD_BF(dst, ldsbase, NH)                                                    \
    _Pragma("unroll") for (int n_ = 0; n_ < 2; ++n_)                                 \
    _Pragma("unroll") for (int ks_ = 0; ks_ < 2; ++ks_)                              \
        dst[n_][ks_] = *(const bf16x8*)((ldsbase) + bRowB + (NH) * 16384 + n_ * 2048 + colsw[ks_]);

#define MFMA_Q(AF, MB, NB, BF)                                                       \
    __builtin_amdgcn_s_setprio(1);                                                   \
    _Pragma("unroll") for (int m_ = 0; m_ < 4; ++m_)                                 \
    _Pragma("unroll") for (int n_ = 0; n_ < 2; ++n_)                                 \
    _Pragma("unroll") for (int ks_ = 0; ks_ < 2; ++ks_)                              \
        acc[(MB) + m_][(NB) + n_] = __builtin_amdgcn_mfma_f32_16x16x32_bf16(         \
            AF[m_][ks_], BF[n_][ks_], acc[(MB) + m_][(NB) + n_], 0, 0, 0);           \
    __builtin_amdgcn_s_setprio(0);

// body(t): entered right after BAR-A(t) with afr0/b0f/b1f(t) loaded.
// AC/BC = bufs of tile t; AO/BO = bufs of tile t+1; KT = t*64.
#define TILE_2B(AC, BC, AO, BO, KT)                                                  \
    MFMA_Q(afr0, 0, 0, b0f); MFMA_Q(afr0, 0, 2, b1f);                                \
    LOAD_AF(afr1, AC, 1);                                                            \
    ST(pB0, (KT) + 128, BC, 0);   ST(pB1, (KT) + 128, BC, 64);                       \
    ST(pB2, (KT) + 128, BC, 128); ST(pB3, (KT) + 128, BC, 192);                      \
    WAIT_VM(4);                                                                      \
    BARRIER();                                                                       \
    MFMA_Q(afr1, 4, 2, b1f); MFMA_Q(afr1, 4, 0, b0f);                                \
    LOAD_AF(afr0, AO, 0); LOAD_BF(b0f, BO, 0); LOAD_BF(b1f, BO, 1);                  \
    ST(pA0, (KT) + 128, AC, 0);   ST(pA2, (KT) + 128, AC, 128);                      \
    ST(pA1, (KT) + 128, AC, 64);  ST(pA3, (KT) + 128, AC, 192);                      \
    BARRIER();

__global__ __launch_bounds__(512, 2) void gemm256_kernel(
    const __bf16* __restrict__ Xb, const __bf16* __restrict__ Wt,
    const float* __restrict__ bias, float* __restrict__ out) {
    extern __shared__ __align__(16) char smem[];
    const int tid  = threadIdx.x;
    const int lane = tid & 63;
    const int wave = tid >> 6;
    const int wr = wave >> 2;   // 0..1
    const int wn = wave & 3;    // 0..3

    const int bid = blockIdx.x;
    const int wg = (bid & 7) * 128 + (bid >> 3);   // XCD swizzle, 1024 % 8 == 0
    const int m0 = (wg >> 4) * 256;
    const int n0 = (wg & 15) * 256;

    char* A0 = smem;
    char* B0 = smem + 32768;
    char* A1 = smem + 65536;
    char* B1 = smem + 98304;

    // staging constants: thread covers row (row0 + srow), 16B group (tid&7)
    const int srow = tid >> 3;
    const int scol = ((tid & 7) ^ (srow & 7)) << 3;   // inverse-swizzled source col (elems)
    const int sldsoff = wave * 1024;                  // wave-uniform LDS offset in chunk

    // hoisted per-thread stage source pointers (A rows 0/64/128/192; B permuted)
    const __bf16* pA0 = Xb + (size_t)(m0 + 0   + srow) * K_DIM + scol;
    const __bf16* pA1 = Xb + (size_t)(m0 + 64  + srow) * K_DIM + scol;
    const __bf16* pA2 = Xb + (size_t)(m0 + 128 + srow) * K_DIM + scol;
    const __bf16* pA3 = Xb + (size_t)(m0 + 192 + srow) * K_DIM + scol;
#define BPERM(P) ((((P) >> 5) & 3) * 64 + (((P) >> 7) & 1) * 32 + ((P) & 31))
    const __bf16* pB0 = Wt + (size_t)(n0 + BPERM(0   + srow)) * K_DIM + scol;
    const __bf16* pB1 = Wt + (size_t)(n0 + BPERM(64  + srow)) * K_DIM + scol;
    const __bf16* pB2 = Wt + (size_t)(n0 + BPERM(128 + srow)) * K_DIM + scol;
    const __bf16* pB3 = Wt + (size_t)(n0 + BPERM(192 + srow)) * K_DIM + scol;

    // frag-read constants (R4-verified conflict-free pattern)
    int colsw[2];
#pragma unroll
    for (int ks = 0; ks < 2; ++ks)
        colsw[ks] = ((ks * 32 + (lane >> 4) * 8) ^ ((lane & 7) * 8)) << 1;
    const int aRowB = (wr * 128 + (lane & 15)) * 128;
    const int bRowB = (wn * 32 + (lane & 15)) * 128;

    f32x4 acc[8][4] = {};
    bf16x8 afr0[4][2], afr1[4][2], b0f[2][2], b1f[2][2];

    // ---- prologue: A(0), B(0), B(1) (12 loads, FIFO order); VM(4) keeps B(1);
    //      then reads1(0) + stage A(1)->A1; BAR-A(0). Invariant [B(1) 4, A(1) 4].
    ST(pA0, 0, A0, 0);   ST(pA2, 0, A0, 128);
    ST(pA1, 0, A0, 64);  ST(pA3, 0, A0, 192);
    ST(pB0, 0, B0, 0);   ST(pB1, 0, B0, 64);
    ST(pB2, 0, B0, 128); ST(pB3, 0, B0, 192);
    ST(pB0, 64, B1, 0);  ST(pB1, 64, B1, 64);
    ST(pB2, 64, B1, 128); ST(pB3, 64, B1, 192);
    WAIT_VM(4);
    BARRIER();
    LOAD_AF(afr0, A0, 0); LOAD_BF(b0f, B0, 0); LOAD_BF(b1f, B0, 1);
    ST(pA0, 64, A1, 0);  ST(pA2, 64, A1, 128);
    ST(pA1, 64, A1, 64); ST(pA3, 64, A1, 192);
    BARRIER();

    // ---- main loop: tiles 0..61 (stages reference B(t+2), A(t+2) <= 63)
    for (int it = 0; it < 31; ++it) {
        const int kt = it * 128;
        TILE_2B(A0, B0, A1, B1, kt);
        TILE_2B(A1, B1, A0, B0, kt + 64);
    }

    // ---- tile 62 (A0/B0): no stages; VM(0) drains B(63)+A(63) pre-BAR-B
    MFMA_Q(afr0, 0, 0, b0f); MFMA_Q(afr0, 0, 2, b1f);
    LOAD_AF(afr1, A0, 1);
    WAIT_VM(0);
    BARRIER();
    MFMA_Q(afr1, 4, 2, b1f); MFMA_Q(afr1, 4, 0, b0f);
    LOAD_AF(afr0, A1, 0); LOAD_BF(b0f, B1, 0); LOAD_BF(b1f, B1, 1);
    BARRIER();

    // ---- tile 63 (A1/B1): barrier-free
    MFMA_Q(afr0, 0, 0, b0f); MFMA_Q(afr0, 0, 2, b1f);
    LOAD_AF(afr1, A1, 1);
    MFMA_Q(afr1, 4, 2, b1f); MFMA_Q(afr1, 4, 0, b0f);

    // ---- epilogue: LDS-coalesced C-write (R20, verified), 2 chunks of 128 rows.
    float* cbuf = (float*)smem;
#pragma unroll
    for (int mh = 0; mh < 2; ++mh) {
        BARRIER();   // mh=0: protect tile63 LDS reads; mh=1: protect chunk0 reads
#pragma unroll
        for (int m = 0; m < 4; ++m)
#pragma unroll
            for (int nh = 0; nh < 2; ++nh)
#pragma unroll
                for (int n = 0; n < 2; ++n) {
                    const int lc = wn * 64 + nh * 32 + n * 16 + (lane & 15);
                    const float bv = bias[n0 + lc];
                    const f32x4 a = acc[mh * 4 + m][nh * 2 + n];
#pragma unroll
                    for (int j = 0; j < 4; ++j) {
                        const int r = wr * 64 + m * 16 + (lane >> 4) * 4 + j;
                        cbuf[r * 256 + ((lc + 4 * r) & 255)] = a[j] + bv;
                    }
                }
        BARRIER();
#pragma unroll
        for (int i = 0; i < 16; ++i) {
            const int idx = i * 512 + tid;
            const int r = idx >> 6;
            const int c4 = idx & 63;
            const f32x4 v = *(const f32x4*)&cbuf[r * 256 + (((c4 + r) & 63) << 2)];
            const int grow = m0 + mh * 64 + r + ((r >> 6) << 6);
            __builtin_nontemporal_store(v,
                (f32x4*)&out[(size_t)grow * N_DIM + n0 + c4 * 4]);
        }
    }
}

extern "C" void kernel_launch(void* const* d_in, const int* in_sizes, int n_in,
                              void* d_out, int out_size, void* d_ws, size_t ws_size,
                              hipStream_t stream) {
    const float* x    = (const float*)d_in[0];
    const float* W    = (const float*)d_in[1];
    const float* bias = (const float*)d_in[2];
    const float* lA   = (const float*)d_in[3];
    const float* lB   = (const float*)d_in[4];
    float* out = (float*)d_out;

    __bf16* Xb = (__bf16*)d_ws;
    __bf16* Wt = (__bf16*)((char*)d_ws + (size_t)M_DIM * K_DIM * 2);

    cast_x_kernel<<<2048, 256, 0, stream>>>(x, Xb, (size_t)M_DIM * K_DIM);
    prep_w_kernel<<<dim3(N_DIM / 32, K_DIM / 32), dim3(32, 8), 0, stream>>>(W, lA, lB, Wt);

    (void)hipFuncSetAttribute((const void*)gemm256_kernel,
                              hipFuncAttributeMaxDynamicSharedMemorySize, 131072);
    gemm256_kernel<<<1024, 512, 131072, stream>>>(Xb, Wt, bias, out);
}

// Round 22
// 540.069 us; speedup vs baseline: 1.7246x; 1.7246x over previous
//
#include <hip/hip_runtime.h>
#include <hip/hip_bf16.h>

// out[M,N] = X[M,K] @ W[K,N] + (X@A)@B + bias;  M=16384, N=K=4096.
// P1: X -> bf16.  P2: Wt[n][k] = bf16(W[k][n] + lora).  G: 256x256 MFMA GEMM,
// 4 phases / 4 barriers / ONE vmcnt per K-tile (R19) + LDS-coalesced epilogue.
// (R20 — session-best verified kernel.)

typedef __attribute__((ext_vector_type(8))) __bf16 bf16x8;
typedef __attribute__((ext_vector_type(4))) float f32x4;

#define M_DIM 16384
#define N_DIM 4096
#define K_DIM 4096

__device__ __forceinline__ void async16(const void* g, void* l) {
    __builtin_amdgcn_global_load_lds((const __attribute__((address_space(1))) void*)g,
                                     (__attribute__((address_space(3))) void*)l,
                                     16, 0, 0);
}

// ---------------- P1: cast X to bf16 ----------------
__global__ void cast_x_kernel(const float* __restrict__ x, __bf16* __restrict__ xb, size_t n) {
    size_t i0 = ((size_t)blockIdx.x * blockDim.x + threadIdx.x) * 8;
    size_t stride = (size_t)gridDim.x * blockDim.x * 8;
    for (size_t i = i0; i < n; i += stride) {
        f32x4 v0 = __builtin_nontemporal_load((const f32x4*)(x + i));
        f32x4 v1 = __builtin_nontemporal_load((const f32x4*)(x + i + 4));
        bf16x8 o;
        o[0] = (__bf16)v0[0]; o[1] = (__bf16)v0[1]; o[2] = (__bf16)v0[2]; o[3] = (__bf16)v0[3];
        o[4] = (__bf16)v1[0]; o[5] = (__bf16)v1[1]; o[6] = (__bf16)v1[2]; o[7] = (__bf16)v1[3];
        *(bf16x8*)(xb + i) = o;
    }
}

// ---------------- P2: Wt[n][k] = bf16(W[k][n] + lora) ----------------
__global__ void prep_w_kernel(const float* __restrict__ W, const float* __restrict__ A,
                              const float* __restrict__ Bm, __bf16* __restrict__ Wt) {
    __shared__ float Ws[32][33];
    __shared__ float As[32][16];
    __shared__ float Bs[16][32];
    const int tx = threadIdx.x;
    const int ty = threadIdx.y;
    const int t = ty * 32 + tx;
    const int n0 = blockIdx.x * 32;
    const int k0 = blockIdx.y * 32;

#pragma unroll
    for (int i = 0; i < 4; ++i) {
        int k = ty + i * 8;
        Ws[k][tx] = W[(size_t)(k0 + k) * N_DIM + n0 + tx];
    }
    for (int i = t; i < 512; i += 256)
        As[i >> 4][i & 15] = A[(size_t)(k0 + (i >> 4)) * 16 + (i & 15)];
    for (int i = t; i < 512; i += 256)
        Bs[i >> 5][i & 31] = Bm[(size_t)(i >> 5) * N_DIM + n0 + (i & 31)];
    __syncthreads();

    float a[16];
#pragma unroll
    for (int r = 0; r < 16; ++r) a[r] = As[tx][r];
#pragma unroll
    for (int i = 0; i < 4; ++i) {
        int n = ty + i * 8;
        float acc = Ws[tx][n];
#pragma unroll
        for (int r = 0; r < 16; ++r) acc += a[r] * Bs[r][n];
        Wt[(size_t)(n0 + n) * K_DIM + k0 + tx] = (__bf16)acc;
    }
}

// ---------------- G: 256x256, single-vmcnt sound 4-phase K-tiles ----------------
// 512 threads = 8 waves (2 wr x 4 wn). Per wave 128x64 out = 8x4 frags of 16x16.
// LDS: 2 bufs x (A[256][64] + B[256][64]) bf16 = 128 KiB, col-swizzle g -> g^(row&7).
// B rows nh-permuted: phys p = nh*128 + wn*32 + s <-> logical n = wn*64+nh*32+s.
// Stage slots: q1: {B-HT0(t+1)->BO, A-HT1(t+1)->AO}; q3: A-HT0(t+2)->AC;
//              q4: B-HT1(t+2)->BC.  ONE wait: VM(4) pre-BAR4.
// FIFO: entering q1(t) = [q3(t-1), q4(t-1)] = 4; +4+2+2 = 12 -> VM(4) drains all
// of tile t+1's data before BAR4(t).  WAR: each staged region's readers complete
// >=1 barrier before the stage (verified per slot).  Epilogue: LDS-coalesced
// C-write (rotated rows, full-128B-line NT stores, no RMW).

#define WAIT_VM(N) asm volatile("s_waitcnt vmcnt(" #N ")" ::: "memory")
#define BARRIER() do { asm volatile("" ::: "memory"); __builtin_amdgcn_s_barrier(); asm volatile("" ::: "memory"); } while (0)

#define ST(ptr, koff, ldsbase, row0) \
    async16((ptr) + (koff), (ldsbase) + (row0) * 128 + sldsoff)

#define LOAD_AF(dst, ldsbase, MH)                                                    \
    _Pragma("unroll") for (int m_ = 0; m_ < 4; ++m_)                                 \
    _Pragma("unroll") for (int ks_ = 0; ks_ < 2; ++ks_)                              \
        dst[m_][ks_] = *(const bf16x8*)((ldsbase) + aRowB + (MH) * 8192 + m_ * 2048 + colsw[ks_]);

#define LOAD_BF(dst, ldsbase, NH)                                                    \
    _Pragma("unroll") for (int n_ = 0; n_ < 2; ++n_)                                 \
    _Pragma("unroll") for (int ks_ = 0; ks_ < 2; ++ks_)                              \
        dst[n_][ks_] = *(const bf16x8*)((ldsbase) + bRowB + (NH) * 16384 + n_ * 2048 + colsw[ks_]);

#define MFMA_Q(AF, MB, NB, BF)                                                       \
    __builtin_amdgcn_s_setprio(1);                                                   \
    _Pragma("unroll") for (int m_ = 0; m_ < 4; ++m_)                                 \
    _Pragma("unroll") for (int n_ = 0; n_ < 2; ++n_)                                 \
    _Pragma("unroll") for (int ks_ = 0; ks_ < 2; ++ks_)                              \
        acc[(MB) + m_][(NB) + n_] = __builtin_amdgcn_mfma_f32_16x16x32_bf16(         \
            AF[m_][ks_], BF[n_][ks_], acc[(MB) + m_][(NB) + n_], 0, 0, 0);           \
    __builtin_amdgcn_s_setprio(0);

#define TILE_FULL(AC, BC, AO, BO, KT)                                                \
    LOAD_AF(afr0, AC, 0); LOAD_BF(b0f, BC, 0);                                       \
    ST(pB0, (KT) + 64, BO, 0);    ST(pB1, (KT) + 64, BO, 64);                        \
    ST(pA1, (KT) + 64, AO, 64);   ST(pA3, (KT) + 64, AO, 192);                       \
    BARRIER(); MFMA_Q(afr0, 0, 0, b0f);                                              \
    LOAD_BF(b1f, BC, 1);                                                             \
    BARRIER(); MFMA_Q(afr0, 0, 2, b1f);                                              \
    LOAD_AF(afr1, AC, 1);                                                            \
    ST(pA0, (KT) + 128, AC, 0);   ST(pA2, (KT) + 128, AC, 128);                      \
    BARRIER(); MFMA_Q(afr1, 4, 2, b1f);                                              \
    ST(pB2, (KT) + 128, BC, 128); ST(pB3, (KT) + 128, BC, 192);                      \
    WAIT_VM(4);                                                                      \
    BARRIER(); MFMA_Q(afr1, 4, 0, b0f);

__global__ __launch_bounds__(512, 2) void gemm256_kernel(
    const __bf16* __restrict__ Xb, const __bf16* __restrict__ Wt,
    const float* __restrict__ bias, float* __restrict__ out) {
    extern __shared__ __align__(16) char smem[];
    const int tid  = threadIdx.x;
    const int lane = tid & 63;
    const int wave = tid >> 6;
    const int wr = wave >> 2;   // 0..1
    const int wn = wave & 3;    // 0..3

    const int bid = blockIdx.x;
    const int wg = (bid & 7) * 128 + (bid >> 3);   // XCD swizzle, 1024 % 8 == 0
    const int m0 = (wg >> 4) * 256;
    const int n0 = (wg & 15) * 256;

    char* A0 = smem;
    char* B0 = smem + 32768;
    char* A1 = smem + 65536;
    char* B1 = smem + 98304;

    // staging constants: thread covers row (row0 + srow), 16B group (tid&7)
    const int srow = tid >> 3;
    const int scol = ((tid & 7) ^ (srow & 7)) << 3;   // inverse-swizzled source col (elems)
    const int sldsoff = wave * 1024;                  // wave-uniform LDS offset in chunk

    // hoisted per-thread stage source pointers (A rows 0/64/128/192; B permuted)
    const __bf16* pA0 = Xb + (size_t)(m0 + 0   + srow) * K_DIM + scol;
    const __bf16* pA1 = Xb + (size_t)(m0 + 64  + srow) * K_DIM + scol;
    const __bf16* pA2 = Xb + (size_t)(m0 + 128 + srow) * K_DIM + scol;
    const __bf16* pA3 = Xb + (size_t)(m0 + 192 + srow) * K_DIM + scol;
#define BPERM(P) ((((P) >> 5) & 3) * 64 + (((P) >> 7) & 1) * 32 + ((P) & 31))
    const __bf16* pB0 = Wt + (size_t)(n0 + BPERM(0   + srow)) * K_DIM + scol;
    const __bf16* pB1 = Wt + (size_t)(n0 + BPERM(64  + srow)) * K_DIM + scol;
    const __bf16* pB2 = Wt + (size_t)(n0 + BPERM(128 + srow)) * K_DIM + scol;
    const __bf16* pB3 = Wt + (size_t)(n0 + BPERM(192 + srow)) * K_DIM + scol;

    // frag-read constants (R4-verified conflict-free pattern)
    int colsw[2];
#pragma unroll
    for (int ks = 0; ks < 2; ++ks)
        colsw[ks] = ((ks * 32 + (lane >> 4) * 8) ^ ((lane & 7) * 8)) << 1;
    const int aRowB = (wr * 128 + (lane & 15)) * 128;
    const int bRowB = (wn * 32 + (lane & 15)) * 128;

    f32x4 acc[8][4] = {};
    bf16x8 afr0[4][2], afr1[4][2], b0f[2][2], b1f[2][2];

    // ---- prologue: tile0 (8 loads) + {A-HT0(1), B-HT1(1)} in slot-FIFO order;
    //      VM(4) drains tile0 exactly -> invariant [A-HT0(1) 2, B-HT1(1) 2].
    ST(pA0, 0, A0, 0);    ST(pA2, 0, A0, 128);
    ST(pA1, 0, A0, 64);   ST(pA3, 0, A0, 192);
    ST(pB0, 0, B0, 0);    ST(pB1, 0, B0, 64);
    ST(pB2, 0, B0, 128);  ST(pB3, 0, B0, 192);
    ST(pA0, 64, A1, 0);   ST(pA2, 64, A1, 128);
    ST(pB2, 64, B1, 128); ST(pB3, 64, B1, 192);
    WAIT_VM(4);
    BARRIER();

    // ---- main loop: tiles 0..61 (q1 refs t+1 <= 62, q3/q4 ref t+2 <= 63)
    for (int it = 0; it < 31; ++it) {
        const int kt = it * 128;
        TILE_FULL(A0, B0, A1, B1, kt);
        TILE_FULL(A1, B1, A0, B0, kt + 64);
    }

    // ---- tile 62 (A0/B0): q1 stages t63's {B-HT0->B1, A-HT1->A1}; no q3/q4;
    //      VM(0) pre-BAR4 drains q3(61)=A-HT0(63), q4(61)=B-HT1(63), q1(62).
    LOAD_AF(afr0, A0, 0); LOAD_BF(b0f, B0, 0);
    ST(pB0, 4032, B1, 0);  ST(pB1, 4032, B1, 64);
    ST(pA1, 4032, A1, 64); ST(pA3, 4032, A1, 192);
    BARRIER(); MFMA_Q(afr0, 0, 0, b0f);
    LOAD_BF(b1f, B0, 1);
    BARRIER(); MFMA_Q(afr0, 0, 2, b1f);
    LOAD_AF(afr1, A0, 1);
    BARRIER(); MFMA_Q(afr1, 4, 2, b1f);
    WAIT_VM(0);
    BARRIER(); MFMA_Q(afr1, 4, 0, b0f);

    // ---- tile 63 (A1/B1): all landed + barrier-separated; barrier-free
    LOAD_AF(afr0, A1, 0); LOAD_BF(b0f, B1, 0);
    LOAD_BF(b1f, B1, 1);  LOAD_AF(afr1, A1, 1);
    MFMA_Q(afr0, 0, 0, b0f);
    MFMA_Q(afr0, 0, 2, b1f);
    MFMA_Q(afr1, 4, 2, b1f);
    MFMA_Q(afr1, 4, 0, b0f);

    // ---- epilogue: LDS-coalesced C-write, 2 chunks of 128 rows x 256 cols fp32.
    // Rotated layout: phys float slot = (lc + 4r) & 255; read full permuted rows;
    // NT float4 stores of full 128B lines (no read-modify-write).
    float* cbuf = (float*)smem;
#pragma unroll
    for (int mh = 0; mh < 2; ++mh) {
        BARRIER();   // mh=0: protect tile63 LDS reads; mh=1: protect chunk0 reads
#pragma unroll
        for (int m = 0; m < 4; ++m)
#pragma unroll
            for (int nh = 0; nh < 2; ++nh)
#pragma unroll
                for (int n = 0; n < 2; ++n) {
                    const int lc = wn * 64 + nh * 32 + n * 16 + (lane & 15);
                    const float bv = bias[n0 + lc];
                    const f32x4 a = acc[mh * 4 + m][nh * 2 + n];
#pragma unroll
                    for (int j = 0; j < 4; ++j) {
                        const int r = wr * 64 + m * 16 + (lane >> 4) * 4 + j;
                        cbuf[r * 256 + ((lc + 4 * r) & 255)] = a[j] + bv;
                    }
                }
        BARRIER();
#pragma unroll
        for (int i = 0; i < 16; ++i) {
            const int idx = i * 512 + tid;
            const int r = idx >> 6;
            const int c4 = idx & 63;
            const f32x4 v = *(const f32x4*)&cbuf[r * 256 + (((c4 + r) & 63) << 2)];
            const int grow = m0 + mh * 64 + r + ((r >> 6) << 6);
            __builtin_nontemporal_store(v,
                (f32x4*)&out[(size_t)grow * N_DIM + n0 + c4 * 4]);
        }
    }
}

extern "C" void kernel_launch(void* const* d_in, const int* in_sizes, int n_in,
                              void* d_out, int out_size, void* d_ws, size_t ws_size,
                              hipStream_t stream) {
    const float* x    = (const float*)d_in[0];
    const float* W    = (const float*)d_in[1];
    const float* bias = (const float*)d_in[2];
    const float* lA   = (const float*)d_in[3];
    const float* lB   = (const float*)d_in[4];
    float* out = (float*)d_out;

    __bf16* Xb = (__bf16*)d_ws;
    __bf16* Wt = (__bf16*)((char*)d_ws + (size_t)M_DIM * K_DIM * 2);

    cast_x_kernel<<<2048, 256, 0, stream>>>(x, Xb, (size_t)M_DIM * K_DIM);
    prep_w_kernel<<<dim3(N_DIM / 32, K_DIM / 32), dim3(32, 8), 0, stream>>>(W, lA, lB, Wt);

    (void)hipFuncSetAttribute((const void*)gemm256_kernel,
                              hipFuncAttributeMaxDynamicSharedMemorySize, 131072);
    gemm256_kernel<<<1024, 512, 131072, stream>>>(Xb, Wt, bias, out);
}